// Round 11
// baseline (390.047 us; speedup 1.0000x reference)
//
#include <hip/hip_runtime.h>
#include <hip/hip_fp16.h>

#define NN 100000
#define NE 1600000
#define NG 512
#define F  32

#define BSH    8                              // 256 dst-nodes per bucket
#define BNODES 256
#define NB     ((NN + BNODES - 1) / BNODES)   // 391
#define CAP    5120                           // slots/bucket
#define PCHUNK 4096                           // r6-proven partition chunk
#define NWGP   ((NE + PCHUNK - 1) / PCHUNK)   // 391
#define EPT    8

#define GRID   512                            // == capacity (2 blocks/CU): all resident
#define BT     512
#define L1V    ((NN + 63) / 64)               // 1563  (64 nodes/block, 8 lanes/node)
#define G2V    (NN / 32)                      // 3125  (32 nodes/block, 16 lanes/node)
#define SEGCAP 768                            // 32-node csr segment ~512±23

struct Params {
    const int* src; const int* dst;
    const float* x; const int* batch;
    const float* W1; const float* b1;
    const float* W2; const float* b2;
    const float* Wl; const float* bl;
    int* bar; int* cursor; float* gsum;
    int* rowpack; int* part; int* csr;
    float* dinv; float4* xd; __half2* g1;
    float* out;
};

union __align__(16) SharedU {                  // max member: p1 = 28.8 KB
    struct { int lsort[PCHUNK]; short lbkt[PCHUNK];
             int s_cnt[NB]; int s_lstart[NB]; int s_base[NB]; int wsum[8]; } p1;
    struct { __align__(16) int lcsr[CAP]; int hcnt[BNODES]; int off[BNODES]; int wsum[4]; } p2;
    struct { float W1s[3 * F]; float b1s[F]; } p3;
    struct { __align__(16) float W2s[F * F]; float b2s[F];
             float ts[32][F]; float hs[32][F]; int bat[32]; int lc[SEGCAP]; } p4;
};

// Software grid barrier (plain launch => graph-capture-safe, unlike cooperative).
// Release/acquire via __threadfence; spin uses atomic RMW (coherent point, never
// stale cross-XCD). Counter zeroed by host memset each invocation; targets are
// monotone multiples of GRID so no reset is needed between phases.
__device__ __forceinline__ void gbar(int* ctr, int target) {
    __syncthreads();
    if (threadIdx.x == 0) {
        __threadfence();                       // release: drain + flush dirty L2
        atomicAdd(ctr, 1);
        while (atomicAdd(ctr, 0) < target) { } // device-scope coherent spin
        __threadfence();                       // acquire: invalidate stale caches
    }
    __syncthreads();
}

__global__ void __launch_bounds__(BT, 4) k_mega(Params P) {
    __shared__ SharedU S;
    const int tid = threadIdx.x;
    const int bid = blockIdx.x;

    // ---------- P1: partition (exact r6 body; blocks >= NWGP idle) ----------
    for (int c = bid; c < NWGP; c += GRID) {
        for (int i = tid; i < NB; i += BT) S.p1.s_cnt[i] = 0;
        __syncthreads();
        int e0 = c * PCHUNK;
        int rem = NE - e0;
        int pk[EPT]; short bk[EPT];
        int m = 0;
        if (rem >= PCHUNK) {
#pragma unroll
            for (int h = 0; h < 2; ++h) {
                int e = e0 + h * 2048 + tid * 4;
                int4 s4 = *(const int4*)(P.src + e);
                int4 d4 = *(const int4*)(P.dst + e);
                int ss[4] = {s4.x, s4.y, s4.z, s4.w};
                int dd[4] = {d4.x, d4.y, d4.z, d4.w};
#pragma unroll
                for (int u = 0; u < 4; ++u) {
                    pk[m] = (ss[u] << 8) | (dd[u] & (BNODES - 1));
                    bk[m] = (short)(dd[u] >> BSH);
                    atomicAdd(&S.p1.s_cnt[bk[m]], 1);
                    ++m;
                }
            }
        } else {
#pragma unroll
            for (int k = 0; k < EPT; ++k) {
                int e = e0 + tid + k * BT;
                if (e < NE) {
                    int d = P.dst[e];
                    pk[m] = (P.src[e] << 8) | (d & (BNODES - 1));
                    bk[m] = (short)(d >> BSH);
                    atomicAdd(&S.p1.s_cnt[bk[m]], 1);
                    ++m;
                }
            }
        }
        __syncthreads();
        int cv = (tid < NB) ? S.p1.s_cnt[tid] : 0;
        int v = cv;
#pragma unroll
        for (int o = 1; o < 64; o <<= 1) {
            int t = __shfl_up(v, o, 64);
            if ((tid & 63) >= o) v += t;
        }
        if ((tid & 63) == 63) S.p1.wsum[tid >> 6] = v;
        __syncthreads();
        int add = 0;
        for (int w = 0; w < (tid >> 6); ++w) add += S.p1.wsum[w];
        int excl = v + add - cv;
        if (tid < NB) {
            S.p1.s_lstart[tid] = excl;
            if (cv) S.p1.s_base[tid] = tid * CAP + atomicAdd(&P.cursor[tid], cv);
            S.p1.s_cnt[tid] = 0;   // reuse as rank counter
        }
        __syncthreads();
        for (int k = 0; k < m; ++k) {
            int b = bk[k];
            int r = S.p1.s_lstart[b] + atomicAdd(&S.p1.s_cnt[b], 1);
            S.p1.lsort[r] = pk[k];
            S.p1.lbkt[r]  = (short)b;
        }
        __syncthreads();
        int cnt = min(rem, PCHUNK);
        for (int i = tid; i < cnt; i += BT) {
            int b = S.p1.lbkt[i];
            P.part[S.p1.s_base[b] + (i - S.p1.s_lstart[b])] = S.p1.lsort[i];
        }
        __syncthreads();
    }
    gbar(P.bar, GRID * 1);

    // ---------- P2: build (512-thread adaptation of r6 body) ----------
    for (int b = bid; b < NB; b += GRID) {
        int node0 = b << BSH;
        int s0 = b * CAP;
        int ec = P.cursor[b];
        if (tid < BNODES) S.p2.hcnt[tid] = 0;
        __syncthreads();
        int ctail = ec & ~3;
        for (int i = tid * 4; i < ctail; i += BT * 4) {
            int4 p = *(const int4*)(P.part + s0 + i);
            atomicAdd(&S.p2.hcnt[p.x & (BNODES - 1)], 1);
            atomicAdd(&S.p2.hcnt[p.y & (BNODES - 1)], 1);
            atomicAdd(&S.p2.hcnt[p.z & (BNODES - 1)], 1);
            atomicAdd(&S.p2.hcnt[p.w & (BNODES - 1)], 1);
        }
        if (tid < ec - ctail) atomicAdd(&S.p2.hcnt[P.part[s0 + ctail + tid] & (BNODES - 1)], 1);
        __syncthreads();
        int c = (tid < BNODES) ? S.p2.hcnt[tid] : 0;
        int v = c;
#pragma unroll
        for (int o = 1; o < 64; o <<= 1) {
            int t = __shfl_up(v, o, 64);
            if ((tid & 63) >= o) v += t;
        }
        if ((tid & 63) == 63 && tid < BNODES) S.p2.wsum[tid >> 6] = v;
        __syncthreads();
        int add = 0;
        if (tid < BNODES) for (int w = 0; w < (tid >> 6); ++w) add += S.p2.wsum[w];
        int excl = v + add - c;
        int n = node0 + tid;
        if (tid < BNODES) {
            if (n < NN) {
                P.rowpack[n] = ((s0 + excl) << 10) | c;
                float d = rsqrtf((float)c + 1.0f);
                P.dinv[n] = d;
                P.xd[n] = make_float4(d * P.x[n * 3 + 0], d * P.x[n * 3 + 1],
                                      d * P.x[n * 3 + 2], d);
            }
            S.p2.off[tid] = excl;
        }
        __syncthreads();
        for (int i = tid * 4; i < ctail; i += BT * 4) {
            int4 p = *(const int4*)(P.part + s0 + i);
            { int pos = atomicAdd(&S.p2.off[p.x & (BNODES - 1)], 1); S.p2.lcsr[pos] = p.x >> 8; }
            { int pos = atomicAdd(&S.p2.off[p.y & (BNODES - 1)], 1); S.p2.lcsr[pos] = p.y >> 8; }
            { int pos = atomicAdd(&S.p2.off[p.z & (BNODES - 1)], 1); S.p2.lcsr[pos] = p.z >> 8; }
            { int pos = atomicAdd(&S.p2.off[p.w & (BNODES - 1)], 1); S.p2.lcsr[pos] = p.w >> 8; }
        }
        if (tid < ec - ctail) {
            int p = P.part[s0 + ctail + tid];
            int pos = atomicAdd(&S.p2.off[p & (BNODES - 1)], 1);
            S.p2.lcsr[pos] = p >> 8;
        }
        __syncthreads();
        for (int i = tid * 4; i < ctail; i += BT * 4)
            *(int4*)(P.csr + s0 + i) = *(const int4*)(S.p2.lcsr + i);
        if (tid < ec - ctail) P.csr[s0 + ctail + tid] = S.p2.lcsr[ctail + tid];
        __syncthreads();
    }
    gbar(P.bar, GRID * 2);

    // ---------- P3: l1 (64 nodes/block, 8 lanes/node) ----------
    if (tid < 3 * F) S.p3.W1s[tid] = P.W1[tid];
    if (tid < F)     S.p3.b1s[tid] = P.b1[tid];
    __syncthreads();
    {
        int nl = tid >> 3, l8 = tid & 7;
        for (int vb = bid; vb < L1V; vb += GRID) {
            int n = vb * 64 + nl;
            if (n < NN) {
                int pack = P.rowpack[n];
                int beg = pack >> 10, deg = pack & 1023;
                float ax = 0.0f, ay = 0.0f, az = 0.0f;
                for (int e = beg + l8; e < beg + deg; e += 8) {
                    float4 vv = P.xd[P.csr[e]];
                    ax += vv.x; ay += vv.y; az += vv.z;
                }
#pragma unroll
                for (int o = 1; o < 8; o <<= 1) {
                    ax += __shfl_xor(ax, o, 8);
                    ay += __shfl_xor(ay, o, 8);
                    az += __shfl_xor(az, o, 8);
                }
                float4 sf = P.xd[n];
                float dn = sf.w;
                float cx = dn * (ax + sf.x), cy = dn * (ay + sf.y), cz = dn * (az + sf.z);
                __half2 tmp[2];
#pragma unroll
                for (int t = 0; t < 2; ++t) {
                    int f0 = l8 * 4 + 2 * t, f1 = f0 + 1;
                    float v0 = cx * S.p3.W1s[f0] + cy * S.p3.W1s[F + f0]
                             + cz * S.p3.W1s[2 * F + f0] + S.p3.b1s[f0];
                    float v1 = cx * S.p3.W1s[f1] + cy * S.p3.W1s[F + f1]
                             + cz * S.p3.W1s[2 * F + f1] + S.p3.b1s[f1];
                    tmp[t] = __floats2half2_rn(dn * fmaxf(v0, 0.0f), dn * fmaxf(v1, 0.0f));
                }
                *(uint2*)(P.g1 + (size_t)n * 16 + l8 * 2) = *(const uint2*)tmp;
            }
        }
    }
    gbar(P.bar, GRID * 3);

    // ---------- P4: gather2p (32 nodes/block, 16 lanes/node, LDS csr segment) ----------
    if (tid < 256) ((float4*)S.p4.W2s)[tid] = ((const float4*)P.W2)[tid];
    if (tid < F / 4) ((float4*)S.p4.b2s)[tid] = ((const float4*)P.b2)[tid];
    for (int vb = bid; vb < G2V; vb += GRID) {
        __syncthreads();                        // weights visible; prev-iter pool done
        int nb = vb * 32;
        if (tid < 32) S.p4.bat[tid] = P.batch[nb + tid];
        int rp0 = P.rowpack[nb];
        int rpL = P.rowpack[nb + 31];
        int beg0 = rp0 >> 10;
        int seg  = (rpL >> 10) + (rpL & 1023) - beg0;
        bool useLds = (seg <= SEGCAP);
        if (useLds) {
            for (int i = tid; i < seg; i += BT) S.p4.lc[i] = P.csr[beg0 + i];
        }
        __syncthreads();
        int nl = tid >> 4, j = tid & 15;
        int n = nb + nl;                        // always < NN (G2V*32 == NN)
        {
            int pack = P.rowpack[n];
            int deg = pack & 1023;
            float ax = 0.0f, ay = 0.0f;
            if (useLds) {
                int e = (pack >> 10) - beg0;
                int end = e + deg;
                for (; e + 7 < end; e += 8) {
                    int s0 = S.p4.lc[e],     s1 = S.p4.lc[e + 1], s2 = S.p4.lc[e + 2], s3 = S.p4.lc[e + 3];
                    int s4 = S.p4.lc[e + 4], s5 = S.p4.lc[e + 5], s6 = S.p4.lc[e + 6], s7 = S.p4.lc[e + 7];
                    float2 v0 = __half22float2(P.g1[s0 * 16 + j]);
                    float2 v1 = __half22float2(P.g1[s1 * 16 + j]);
                    float2 v2 = __half22float2(P.g1[s2 * 16 + j]);
                    float2 v3 = __half22float2(P.g1[s3 * 16 + j]);
                    float2 v4 = __half22float2(P.g1[s4 * 16 + j]);
                    float2 v5 = __half22float2(P.g1[s5 * 16 + j]);
                    float2 v6 = __half22float2(P.g1[s6 * 16 + j]);
                    float2 v7 = __half22float2(P.g1[s7 * 16 + j]);
                    ax += ((v0.x + v1.x) + (v2.x + v3.x)) + ((v4.x + v5.x) + (v6.x + v7.x));
                    ay += ((v0.y + v1.y) + (v2.y + v3.y)) + ((v4.y + v5.y) + (v6.y + v7.y));
                }
                for (; e + 3 < end; e += 4) {
                    int s0 = S.p4.lc[e], s1 = S.p4.lc[e + 1], s2 = S.p4.lc[e + 2], s3 = S.p4.lc[e + 3];
                    float2 v0 = __half22float2(P.g1[s0 * 16 + j]);
                    float2 v1 = __half22float2(P.g1[s1 * 16 + j]);
                    float2 v2 = __half22float2(P.g1[s2 * 16 + j]);
                    float2 v3 = __half22float2(P.g1[s3 * 16 + j]);
                    ax += (v0.x + v1.x) + (v2.x + v3.x);
                    ay += (v0.y + v1.y) + (v2.y + v3.y);
                }
                for (; e < end; ++e) {
                    float2 v = __half22float2(P.g1[S.p4.lc[e] * 16 + j]);
                    ax += v.x; ay += v.y;
                }
            } else {                            // statistical-overflow guard path
                int e = pack >> 10;
                int end = e + deg;
                for (; e < end; ++e) {
                    float2 v = __half22float2(P.g1[P.csr[e] * 16 + j]);
                    ax += v.x; ay += v.y;
                }
            }
            float dn = P.dinv[n];
            float2 sf = __half22float2(P.g1[n * 16 + j]);
            S.p4.ts[nl][2 * j]     = dn * (ax + sf.x);
            S.p4.ts[nl][2 * j + 1] = dn * (ay + sf.y);
        }
        __syncthreads();
        {
            int f = tid & 31;
            int nn0 = tid >> 5;                 // 0..15
#pragma unroll
            for (int pass = 0; pass < 2; ++pass) {
                int nn = nn0 + pass * 16;
                float acc = S.p4.b2s[f];
#pragma unroll
                for (int k = 0; k < F; ++k) acc += S.p4.ts[nn][k] * S.p4.W2s[k * F + f];
                S.p4.hs[nn][f] = fmaxf(acc, 0.0f);
            }
        }
        __syncthreads();
        if (tid < F) {
            int g0 = S.p4.bat[0], gmax = S.p4.bat[31];
            for (int g = g0; g <= gmax; ++g) {
                float s = 0.0f;
                for (int i = 0; i < 32; ++i) if (S.p4.bat[i] == g) s += S.p4.hs[i][tid];
                atomicAdd(&P.gsum[g * F + tid], s);
            }
        }
    }
    gbar(P.bar, GRID * 4);

    // ---------- P5: head (block 0; NG == BT) ----------
    if (bid == 0) {
        int g = tid;
        int lo = 0, hi = NN;
        while (lo < hi) { int m = (lo + hi) >> 1; if (P.batch[m] < g) lo = m + 1; else hi = m; }
        int s = lo;
        lo = 0; hi = NN;
        while (lo < hi) { int m = (lo + hi) >> 1; if (P.batch[m] < g + 1) lo = m + 1; else hi = m; }
        float inv = 1.0f / fmaxf((float)(lo - s), 1.0f);
        float a0 = 0.0f, a1 = 0.0f;
#pragma unroll
        for (int k = 0; k < F; ++k) {
            float m = P.gsum[g * F + k] * inv;
            a0 += m * P.Wl[k * 2 + 0];
            a1 += m * P.Wl[k * 2 + 1];
        }
        P.out[g * 2 + 0] = a0 + P.bl[0];
        P.out[g * 2 + 1] = a1 + P.bl[1];
    }
}

extern "C" void kernel_launch(void* const* d_in, const int* in_sizes, int n_in,
                              void* d_out, int out_size, void* d_ws, size_t ws_size,
                              hipStream_t stream) {
    const float* x     = (const float*)d_in[0];
    const int*   eidx  = (const int*)d_in[1];   // int32 per harness contract
    const int*   batch = (const int*)d_in[2];
    const float* W1    = (const float*)d_in[3];
    const float* b1    = (const float*)d_in[4];
    const float* W2    = (const float*)d_in[5];
    const float* b2    = (const float*)d_in[6];
    const float* Wl    = (const float*)d_in[7];
    const float* bl    = (const float*)d_in[8];
    float*       out   = (float*)d_out;

    const int* src = eidx;
    const int* dst = eidx + NE;

    // ---- workspace layout, 128B-aligned chunks ----
    char* base = (char*)d_ws;
    size_t off = 0;
    auto alloc = [&](size_t bytes) {
        void* p = base + off;
        off = (off + bytes + 127) & ~(size_t)127;
        return p;
    };
    // bar + cursor + gsum contiguous -> single memset (zeroed EVERY invocation)
    size_t zbytes = 32 * sizeof(int) + NB * sizeof(int) + (size_t)NG * F * sizeof(float);
    int*     barp    = (int*)alloc(zbytes);
    int*     cursor  = barp + 32;
    float*   gsum    = (float*)(cursor + NB);
    int*     rowpack = (int*)alloc(NN * sizeof(int));
    int*     part    = (int*)alloc((size_t)NB * CAP * sizeof(int));
    int*     csr     = (int*)alloc((size_t)NB * CAP * sizeof(int));
    float*   dinv    = (float*)alloc(NN * sizeof(float));
    float4*  xd      = (float4*)alloc(NN * sizeof(float4));
    __half2* g1      = (__half2*)alloc((size_t)NN * 16 * sizeof(__half2));

    hipMemsetAsync(barp, 0, zbytes, stream);

    Params Pv;
    Pv.src = src; Pv.dst = dst; Pv.x = x; Pv.batch = batch;
    Pv.W1 = W1; Pv.b1 = b1; Pv.W2 = W2; Pv.b2 = b2; Pv.Wl = Wl; Pv.bl = bl;
    Pv.bar = barp; Pv.cursor = cursor; Pv.gsum = gsum; Pv.rowpack = rowpack;
    Pv.part = part; Pv.csr = csr; Pv.dinv = dinv; Pv.xd = xd; Pv.g1 = g1;
    Pv.out = out;

    k_mega<<<dim3(GRID), dim3(BT), 0, stream>>>(Pv);
}

// Round 12
// 154.416 us; speedup vs baseline: 2.5259x; 2.5259x over previous
//
#include <hip/hip_runtime.h>
#include <hip/hip_fp16.h>

#define NN 100000
#define NE 1600000
#define NG 512
#define F  32

#define BSH    8                              // 256 dst-nodes per bucket
#define BNODES 256
#define NB     ((NN + BNODES - 1) / BNODES)   // 391
#define CAP    5120                           // slots/bucket (mean 4092, sigma 64 -> safe)
#define PCHUNK 4096
#define EPT    8                              // edges per thread (PCHUNK/512)
#define NWGP   ((NE + PCHUNK - 1) / PCHUNK)   // 391

// ---- partition: in-LDS counting sort per chunk -> coalesced bucket-run writes ----
__global__ void k_partition(const int* __restrict__ src, const int* __restrict__ dst,
                            int* __restrict__ cursor, int* __restrict__ part) {
    __shared__ int   s_cnt[NB];      // hist, then reused as rank counter
    __shared__ int   s_lstart[NB];
    __shared__ int   s_base[NB];
    __shared__ int   wsum[8];
    __shared__ int   lsort[PCHUNK];
    __shared__ short lbkt[PCHUNK];
    int tid = threadIdx.x;
    for (int i = tid; i < NB; i += 512) s_cnt[i] = 0;
    __syncthreads();
    int e0 = blockIdx.x * PCHUNK;
    int rem = NE - e0;
    int pk[EPT]; short bk[EPT];
    int m = 0;
    if (rem >= PCHUNK) {
        // full chunk: 2x int4 vector loads per thread (16B/lane, fully coalesced)
#pragma unroll
        for (int h = 0; h < 2; ++h) {
            int e = e0 + h * 2048 + tid * 4;
            int4 s4 = *(const int4*)(src + e);
            int4 d4 = *(const int4*)(dst + e);
            int ss[4] = {s4.x, s4.y, s4.z, s4.w};
            int dd[4] = {d4.x, d4.y, d4.z, d4.w};
#pragma unroll
            for (int u = 0; u < 4; ++u) {
                pk[m] = (ss[u] << 8) | (dd[u] & (BNODES - 1));
                bk[m] = (short)(dd[u] >> BSH);
                atomicAdd(&s_cnt[bk[m]], 1);
                ++m;
            }
        }
    } else {
        // tail chunk (2560 edges): scalar guarded path
#pragma unroll
        for (int k = 0; k < EPT; ++k) {
            int e = e0 + tid + k * 512;
            if (e < NE) {
                int d = dst[e];
                pk[m] = (src[e] << 8) | (d & (BNODES - 1));
                bk[m] = (short)(d >> BSH);
                atomicAdd(&s_cnt[bk[m]], 1);
                ++m;
            }
        }
    }
    __syncthreads();
    int cv = (tid < NB) ? s_cnt[tid] : 0;
    int v = cv;
#pragma unroll
    for (int o = 1; o < 64; o <<= 1) {
        int t = __shfl_up(v, o, 64);
        if ((tid & 63) >= o) v += t;
    }
    if ((tid & 63) == 63) wsum[tid >> 6] = v;
    __syncthreads();
    int add = 0;
    for (int w = 0; w < (tid >> 6); ++w) add += wsum[w];
    int excl = v + add - cv;
    if (tid < NB) {
        s_lstart[tid] = excl;
        if (cv) s_base[tid] = tid * CAP + atomicAdd(&cursor[tid], cv);
        s_cnt[tid] = 0;   // reuse as rank counter
    }
    __syncthreads();
    for (int k = 0; k < m; ++k) {
        int b = bk[k];
        int r = s_lstart[b] + atomicAdd(&s_cnt[b], 1);
        lsort[r] = pk[k];
        lbkt[r]  = (short)b;
    }
    __syncthreads();
    int cnt = min(rem, PCHUNK);
    for (int i = tid; i < cnt; i += 512) {
        int b = lbkt[i];
        part[s_base[b] + (i - s_lstart[b])] = lsort[i];   // coalesced per-bucket runs
    }
}

// ---- build: hist + scan -> rowpack/dinv/xd, then rank-scatter + coalesced csr write ----
// also zeroes gsum (runs strictly before gather2p) -> memset shrinks to cursor only
__global__ void k_build(const int* __restrict__ part, const int* __restrict__ cursor,
                        const float* __restrict__ x,
                        int* __restrict__ rowpack, float* __restrict__ dinv,
                        float4* __restrict__ xd, int* __restrict__ csr,
                        float* __restrict__ gsum) {
    __shared__ __align__(16) int lcsr[CAP];
    __shared__ int hcnt[BNODES];
    __shared__ int off[BNODES];
    __shared__ int wsum[4];
    int b = blockIdx.x, tid = threadIdx.x;
    if (b < 64) gsum[b * 256 + tid] = 0.0f;    // 64 blocks x 256 = NG*F, disjoint
    int node0 = b << BSH;
    int s0 = b * CAP;
    int ec = cursor[b];
    hcnt[tid] = 0;
    __syncthreads();
    int ctail = ec & ~3;
    for (int i = tid * 4; i < ctail; i += 1024) {      // int4 vector hist pass
        int4 p = *(const int4*)(part + s0 + i);
        atomicAdd(&hcnt[p.x & (BNODES - 1)], 1);
        atomicAdd(&hcnt[p.y & (BNODES - 1)], 1);
        atomicAdd(&hcnt[p.z & (BNODES - 1)], 1);
        atomicAdd(&hcnt[p.w & (BNODES - 1)], 1);
    }
    if (tid < ec - ctail) atomicAdd(&hcnt[part[s0 + ctail + tid] & (BNODES - 1)], 1);
    __syncthreads();
    int c = hcnt[tid];
    int v = c;
#pragma unroll
    for (int o = 1; o < 64; o <<= 1) {
        int t = __shfl_up(v, o, 64);
        if ((tid & 63) >= o) v += t;
    }
    if ((tid & 63) == 63) wsum[tid >> 6] = v;
    __syncthreads();
    int add = 0;
    for (int w = 0; w < (tid >> 6); ++w) add += wsum[w];
    int excl = v + add - c;
    int n = node0 + tid;
    if (n < NN) {
        rowpack[n] = ((s0 + excl) << 10) | c;
        float d = rsqrtf((float)c + 1.0f);
        dinv[n] = d;
        xd[n] = make_float4(d * x[n * 3 + 0], d * x[n * 3 + 1], d * x[n * 3 + 2], d);
    }
    off[tid] = excl;
    __syncthreads();
    for (int i = tid * 4; i < ctail; i += 1024) {      // int4 rank-scatter (part cache-hot)
        int4 p = *(const int4*)(part + s0 + i);
        { int pos = atomicAdd(&off[p.x & (BNODES - 1)], 1); lcsr[pos] = p.x >> 8; }
        { int pos = atomicAdd(&off[p.y & (BNODES - 1)], 1); lcsr[pos] = p.y >> 8; }
        { int pos = atomicAdd(&off[p.z & (BNODES - 1)], 1); lcsr[pos] = p.z >> 8; }
        { int pos = atomicAdd(&off[p.w & (BNODES - 1)], 1); lcsr[pos] = p.w >> 8; }
    }
    if (tid < ec - ctail) {
        int p = part[s0 + ctail + tid];
        int pos = atomicAdd(&off[p & (BNODES - 1)], 1);
        lcsr[pos] = p >> 8;
    }
    __syncthreads();
    for (int i = tid * 4; i < ctail; i += 1024)        // int4 coalesced write-out
        *(int4*)(csr + s0 + i) = *(const int4*)(lcsr + i);
    if (tid < ec - ctail) csr[s0 + ctail + tid] = lcsr[ctail + tid];
}

// ---- l1: 8 lanes/node gather + shfl-reduce + fused W1/relu -> g1 fp16 (coalesced) ----
#define L1NPB 32                               // nodes per 256-thread block
__global__ void k_l1(const int* __restrict__ rowpack, const int* __restrict__ csr,
                     const float4* __restrict__ xd,
                     const float* __restrict__ W1, const float* __restrict__ b1,
                     __half2* __restrict__ g1) {
    __shared__ float W1s[3 * F];
    __shared__ float b1s[F];
    int tid = threadIdx.x;
    if (tid < 3 * F) W1s[tid] = W1[tid];
    if (tid < F) b1s[tid] = b1[tid];
    __syncthreads();
    int nl = tid >> 3, l8 = tid & 7;
    int n = blockIdx.x * L1NPB + nl;
    if (n >= NN) return;
    int pack = rowpack[n];
    int beg = pack >> 10, deg = pack & 1023;
    float ax = 0.0f, ay = 0.0f, az = 0.0f;
    for (int e = beg + l8; e < beg + deg; e += 8) {     // 8-lane edge stride
        float4 v = xd[csr[e]];
        ax += v.x; ay += v.y; az += v.z;
    }
#pragma unroll
    for (int o = 1; o < 8; o <<= 1) {                   // xor-reduce: all 8 lanes get sums
        ax += __shfl_xor(ax, o, 8);
        ay += __shfl_xor(ay, o, 8);
        az += __shfl_xor(az, o, 8);
    }
    float4 sf = xd[n];
    float dn = sf.w;
    float cx = dn * (ax + sf.x), cy = dn * (ay + sf.y), cz = dn * (az + sf.z);
    __half2 tmp[2];
#pragma unroll
    for (int t = 0; t < 2; ++t) {
        int f0 = l8 * 4 + 2 * t, f1 = f0 + 1;
        float v0 = cx * W1s[f0] + cy * W1s[F + f0] + cz * W1s[2 * F + f0] + b1s[f0];
        float v1 = cx * W1s[f1] + cy * W1s[F + f1] + cz * W1s[2 * F + f1] + b1s[f1];
        tmp[t] = __floats2half2_rn(dn * fmaxf(v0, 0.0f), dn * fmaxf(v1, 0.0f));
    }
    *(uint2*)(g1 + (size_t)n * 16 + l8 * 2) = *(const uint2*)tmp;
}

// ---- gather2p: LDS-staged csr segment + gather g1 + proj2(W2)+relu + pool -> gsum ----
// 16 lanes/node x 4B: 16 consecutive addrs = ONE 64B line per node per instr (r7 lesson).
#define SEGCAP 1024
__global__ void k_gather2p(const int* __restrict__ rowpack, const int* __restrict__ csr,
                           const __half2* __restrict__ g1, const float* __restrict__ dinv,
                           const int* __restrict__ batch,
                           const float* __restrict__ W2, const float* __restrict__ b2,
                           float* __restrict__ gsum) {
    __shared__ __align__(16) float W2s[F * F];
    __shared__ __align__(16) float b2s[F];
    __shared__ float ts[16][F];
    __shared__ float hs[16][F];
    __shared__ int bat[16];
    __shared__ int lc[SEGCAP];
    int tid = threadIdx.x;
    int nb = blockIdx.x * 16;
    ((float4*)W2s)[tid] = ((const float4*)W2)[tid];    // 256 threads x float4 = 1024 floats
    if (tid < F / 4) ((float4*)b2s)[tid] = ((const float4*)b2)[tid];
    if (tid < 16) bat[tid] = batch[nb + tid];
    // ---- stage the block's contiguous csr segment into LDS (coalesced once) ----
    int rp0  = rowpack[nb];
    int rp15 = rowpack[nb + 15];
    int beg0 = rp0 >> 10;
    int seg  = (rp15 >> 10) + (rp15 & 1023) - beg0;
    bool useLds = (seg <= SEGCAP);               // stats: seg ~ 256±16; guard anyway
    if (useLds) {
        for (int i = tid; i < seg; i += 256) lc[i] = csr[beg0 + i];
    }
    __syncthreads();
    int nl = tid >> 4, j = tid & 15;
    int n = nb + nl;
    {
        int pack = rowpack[n];
        int deg = pack & 1023;
        float ax = 0.0f, ay = 0.0f;
        if (useLds) {
            int e = (pack >> 10) - beg0;
            int end = e + deg;
            for (; e + 7 < end; e += 8) {
                int s0 = lc[e],     s1 = lc[e + 1], s2 = lc[e + 2], s3 = lc[e + 3];
                int s4 = lc[e + 4], s5 = lc[e + 5], s6 = lc[e + 6], s7 = lc[e + 7];
                float2 v0 = __half22float2(g1[s0 * 16 + j]);
                float2 v1 = __half22float2(g1[s1 * 16 + j]);
                float2 v2 = __half22float2(g1[s2 * 16 + j]);
                float2 v3 = __half22float2(g1[s3 * 16 + j]);
                float2 v4 = __half22float2(g1[s4 * 16 + j]);
                float2 v5 = __half22float2(g1[s5 * 16 + j]);
                float2 v6 = __half22float2(g1[s6 * 16 + j]);
                float2 v7 = __half22float2(g1[s7 * 16 + j]);
                ax += ((v0.x + v1.x) + (v2.x + v3.x)) + ((v4.x + v5.x) + (v6.x + v7.x));
                ay += ((v0.y + v1.y) + (v2.y + v3.y)) + ((v4.y + v5.y) + (v6.y + v7.y));
            }
            for (; e + 3 < end; e += 4) {
                int s0 = lc[e], s1 = lc[e + 1], s2 = lc[e + 2], s3 = lc[e + 3];
                float2 v0 = __half22float2(g1[s0 * 16 + j]);
                float2 v1 = __half22float2(g1[s1 * 16 + j]);
                float2 v2 = __half22float2(g1[s2 * 16 + j]);
                float2 v3 = __half22float2(g1[s3 * 16 + j]);
                ax += (v0.x + v1.x) + (v2.x + v3.x);
                ay += (v0.y + v1.y) + (v2.y + v3.y);
            }
            for (; e < end; ++e) {
                float2 v = __half22float2(g1[lc[e] * 16 + j]);
                ax += v.x; ay += v.y;
            }
        } else {                                   // never in practice; correctness guard
            int e = pack >> 10;
            int end = e + deg;
            for (; e < end; ++e) {
                float2 v = __half22float2(g1[csr[e] * 16 + j]);
                ax += v.x; ay += v.y;
            }
        }
        float dn = dinv[n];
        float2 sf = __half22float2(g1[n * 16 + j]);
        ts[nl][2 * j]     = dn * (ax + sf.x);
        ts[nl][2 * j + 1] = dn * (ay + sf.y);
    }
    __syncthreads();
    {
        int f = tid & 31;
        int nn0 = tid >> 5;           // 0..7
#pragma unroll
        for (int pass = 0; pass < 2; ++pass) {
            int nn = nn0 + pass * 8;
            float acc = b2s[f];
#pragma unroll
            for (int k = 0; k < F; ++k) acc += ts[nn][k] * W2s[k * F + f];
            hs[nn][f] = fmaxf(acc, 0.0f);
        }
    }
    __syncthreads();
    if (tid < F) {
        int g0 = bat[0], gmax = bat[15];
        for (int g = g0; g <= gmax; ++g) {
            float s = 0.0f;
#pragma unroll
            for (int i = 0; i < 16; ++i) if (bat[i] == g) s += hs[i][tid];
            atomicAdd(&gsum[g * F + tid], s);
        }
    }
}

// ---- head: out[g] = (gsum[g]/max(cnt,1)) @ Wl + bl ----
__global__ void k_head(const float* __restrict__ gsum, const int* __restrict__ batch,
                       const float* __restrict__ Wl, const float* __restrict__ bl,
                       float* __restrict__ out) {
    int g = blockIdx.x * blockDim.x + threadIdx.x;
    if (g >= NG) return;
    int lo = 0, hi = NN;
    while (lo < hi) { int m = (lo + hi) >> 1; if (batch[m] < g) lo = m + 1; else hi = m; }
    int s = lo;
    lo = 0; hi = NN;
    while (lo < hi) { int m = (lo + hi) >> 1; if (batch[m] < g + 1) lo = m + 1; else hi = m; }
    float inv = 1.0f / fmaxf((float)(lo - s), 1.0f);
    float a0 = 0.0f, a1 = 0.0f;
#pragma unroll
    for (int k = 0; k < F; ++k) {
        float m = gsum[g * F + k] * inv;
        a0 += m * Wl[k * 2 + 0];
        a1 += m * Wl[k * 2 + 1];
    }
    out[g * 2 + 0] = a0 + bl[0];
    out[g * 2 + 1] = a1 + bl[1];
}

extern "C" void kernel_launch(void* const* d_in, const int* in_sizes, int n_in,
                              void* d_out, int out_size, void* d_ws, size_t ws_size,
                              hipStream_t stream) {
    const float* x     = (const float*)d_in[0];
    const int*   eidx  = (const int*)d_in[1];   // int32 per harness contract
    const int*   batch = (const int*)d_in[2];
    const float* W1    = (const float*)d_in[3];
    const float* b1    = (const float*)d_in[4];
    const float* W2    = (const float*)d_in[5];
    const float* b2    = (const float*)d_in[6];
    const float* Wl    = (const float*)d_in[7];
    const float* bl    = (const float*)d_in[8];
    float*       out   = (float*)d_out;

    const int* src = eidx;
    const int* dst = eidx + NE;

    // ---- workspace layout, 128B-aligned chunks ----
    char* base = (char*)d_ws;
    size_t off = 0;
    auto alloc = [&](size_t bytes) {
        void* p = base + off;
        off = (off + bytes + 127) & ~(size_t)127;
        return p;
    };
    int*     cursor  = (int*)alloc(NB * sizeof(int) + (size_t)NG * F * sizeof(float));
    float*   gsum    = (float*)(cursor + NB);    // zeroed by k_build, not memset
    int*     rowpack = (int*)alloc(NN * sizeof(int));
    int*     part    = (int*)alloc((size_t)NB * CAP * sizeof(int));
    int*     csr     = (int*)alloc((size_t)NB * CAP * sizeof(int));
    float*   dinv    = (float*)alloc(NN * sizeof(float));
    float4*  xd      = (float4*)alloc(NN * sizeof(float4));
    __half2* g1      = (__half2*)alloc((size_t)NN * 16 * sizeof(__half2));

    const int B = 256;
    const int gL1  = (NN + L1NPB - 1) / L1NPB;   // 3125
    const int gG16 = NN / 16;                    // 6250, exact

    hipMemsetAsync(cursor, 0, NB * sizeof(int), stream);   // 1.6 KB only

    // ---- CSR build (2 kernels) ----
    k_partition<<<NWGP, 512, 0, stream>>>(src, dst, cursor, part);
    k_build    <<<NB,   B,   0, stream>>>(part, cursor, x, rowpack, dinv, xd, csr, gsum);

    // ---- layer 1 (8 lanes/node, latency-hidden) ----
    k_l1<<<gL1, B, 0, stream>>>(rowpack, csr, xd, W1, b1, g1);

    // ---- layer 2 gather + proj2 + relu + pool (fused, LDS-staged csr) ----
    k_gather2p<<<gG16, B, 0, stream>>>(rowpack, csr, g1, dinv, batch, W2, b2, gsum);

    // ---- head ----
    k_head<<<(NG + B - 1) / B, B, 0, stream>>>(gsum, batch, Wl, bl, out);
}